// Round 6
// baseline (182.410 us; speedup 1.0000x reference)
//
#include <hip/hip_runtime.h>
#include <math.h>

// Problem constants
#define MM 4
#define BB 256
#define KK 64
#define HH 1024
#define NN 50
#define EE 1225
#define PP 64
#define CTOT 1375   // E + N*3
#define NPAD 1408   // cols padded to 11*128

typedef short short8 __attribute__((ext_vector_type(8)));
typedef float floatx4 __attribute__((ext_vector_type(4)));
typedef unsigned short ushort;

__device__ __forceinline__ ushort f2bf(float f) {
    union { float f; unsigned u; } v; v.f = f;
    unsigned r = v.u + 0x7fffu + ((v.u >> 16) & 1u);
    return (ushort)(r >> 16);
}

__device__ __forceinline__ float logsigm(float l) {
    // log sigmoid(-l) = -(max(l,0) + log1p(exp(-|l|)))
    return -(fmaxf(l, 0.0f) + log1pf(expf(-fabsf(l))));
}

__device__ __forceinline__ float wsum64(float v) {
    #pragma unroll
    for (int m = 1; m < 64; m <<= 1) v += __shfl_xor(v, m);
    return v;
}
__device__ __forceinline__ float wmax64(float v) {
    #pragma unroll
    for (int m = 1; m < 64; m <<= 1) v = fmaxf(v, __shfl_xor(v, m));
    return v;
}

// kA: fused weight transpose (blocks 256..607) + per-graph work (blocks 0..255):
//   h = relu(Z@W1+b1) -> bf16, edge extraction from A, KLD, Sneg/doneRT/gq init.
__global__ __launch_bounds__(256) void kA(const float* __restrict__ mean,
                                          const float* __restrict__ logvar,
                                          const float* __restrict__ eps,
                                          const float* __restrict__ W1,
                                          const float* __restrict__ b1,
                                          const float* __restrict__ WA,
                                          const float* __restrict__ WF,
                                          const float* __restrict__ A,
                                          ushort* __restrict__ hB,
                                          ushort* __restrict__ Wt,
                                          float* __restrict__ Sneg,
                                          int*   __restrict__ edgesG,
                                          int*   __restrict__ cntG,
                                          float* __restrict__ kldG,
                                          int*   __restrict__ doneRT,
                                          int*   __restrict__ gq) {
    const int t = threadIdx.x;
    __shared__ float smem[64 * 65];
    __shared__ int cnt;

    if (blockIdx.x < 256) {
        // ---- per-graph block ----
        const int b = blockIdx.x;
        float4* z4 = (float4*)smem;
        if (t == 0) cnt = 0;
        if (b == 0) {
            if (t < 16) doneRT[t] = 0;
            if (t == 16) *gq = 0;
        }
        if (t < 64) {
            float mv = mean[b * 64 + t];
            float lv = logvar[b * 64 + t];
            float sd = expf(0.5f * lv);
            float4 z;
            z.x = mv + sd * eps[(0 * BB + b) * 64 + t];
            z.y = mv + sd * eps[(1 * BB + b) * 64 + t];
            z.z = mv + sd * eps[(2 * BB + b) * 64 + t];
            z.w = mv + sd * eps[(3 * BB + b) * 64 + t];
            z4[t] = z;
            // KLD (wave 0, one lane per latent dim)
            float term = 0.5f * (expf(lv) + mv * mv - 1.0f - lv);
            term = wsum64(term);
            if (t == 0) kldG[b] = term;
        }
        if (t < 4) Sneg[b * 4 + t] = 0.0f;
        __syncthreads();
        const int j0 = t * 4;
        float acc[4][4] = {};   // [m][jc]
        #pragma unroll 8
        for (int k = 0; k < 64; k++) {
            float4 w = *(const float4*)&W1[k * HH + j0];
            float4 z = z4[k];
            acc[0][0] += z.x * w.x; acc[0][1] += z.x * w.y; acc[0][2] += z.x * w.z; acc[0][3] += z.x * w.w;
            acc[1][0] += z.y * w.x; acc[1][1] += z.y * w.y; acc[1][2] += z.y * w.z; acc[1][3] += z.y * w.w;
            acc[2][0] += z.z * w.x; acc[2][1] += z.z * w.y; acc[2][2] += z.z * w.z; acc[2][3] += z.z * w.w;
            acc[3][0] += z.w * w.x; acc[3][1] += z.w * w.y; acc[3][2] += z.w * w.z; acc[3][3] += z.w * w.w;
        }
        float4 bb = *(const float4*)&b1[j0];
        #pragma unroll
        for (int m = 0; m < 4; m++) {
            unsigned u0 = ((unsigned)f2bf(fmaxf(acc[m][0] + bb.x, 0.f))) |
                          ((unsigned)f2bf(fmaxf(acc[m][1] + bb.y, 0.f)) << 16);
            unsigned u1 = ((unsigned)f2bf(fmaxf(acc[m][2] + bb.z, 0.f))) |
                          ((unsigned)f2bf(fmaxf(acc[m][3] + bb.w, 0.f)) << 16);
            uint2 u; u.x = u0; u.y = u1;
            *(uint2*)&hB[(b * 4 + m) * HH + j0] = u;
        }
        // ---- edge extraction: coalesced scan of A[b], lower triangle ----
        for (int x = t; x < 2500; x += 256) {
            int i = x / NN, j = x - i * NN;
            if (j < i) {
                float a = A[b * 2500 + x];
                if (a != 0.0f) { int id = atomicAdd(&cnt, 1); edgesG[b * 256 + id] = (i << 8) | j; }
            }
        }
        __syncthreads();
        if (t == 0) cntG[b] = cnt;
    } else {
        // ---- Wt[n][k] = transpose of [WA | WF] (bf16, zero-padded cols) ----
        const int id = blockIdx.x - 256;
        const int kt = id & 15, nt = id >> 4;
        float* T = smem;   // [64][65]
        const int k0 = kt * 64, n0 = nt * 64;
        #pragma unroll
        for (int i = 0; i < 16; i++) {
            int x = i * 256 + t;
            int kk = x >> 6, nn = x & 63;
            int gn = n0 + nn, gk = k0 + kk;
            float v = 0.f;
            if (gn < EE)        v = WA[gk * EE + gn];
            else if (gn < CTOT) v = WF[gk * 150 + (gn - EE)];
            T[kk * 65 + nn] = v;
        }
        __syncthreads();
        #pragma unroll
        for (int i = 0; i < 16; i++) {
            int x = i * 256 + t;
            int nn = x >> 6, kk = x & 63;
            Wt[(n0 + nn) * 1024 + k0 + kk] = f2bf(T[kk * 65 + nn]);
        }
    }
}

struct SMg { short As[64][72]; short Bs[128][72]; };
struct SMf {
    int   ip[PP * NN];
    float Lb[EE];
    int   edges[256];
    float lgfs[600];
    float mred[4], wmaxs[4];
    int   gcur;
};
union SMem { SMg g; SMf f; };

// k24: MFMA GEMM (block tile 64x128) with fused epilogue, then work-stealing
// finalization: blocks grab graphs from a global queue once that graph's
// row-group (11 column tiles) is complete (device-scope counter handshake).
__global__ __launch_bounds__(256) void k24(const ushort* __restrict__ hB,
                                           const ushort* __restrict__ Wt,
                                           const float* __restrict__ bA,
                                           const float* __restrict__ bF,
                                           const float* __restrict__ Fx,
                                           const float* __restrict__ coeff,
                                           const int*   __restrict__ perms,
                                           float* __restrict__ Lbar,
                                           float* __restrict__ Sneg,
                                           float* __restrict__ lgF,
                                           const int*   __restrict__ edgesG,
                                           const int*   __restrict__ cntG,
                                           const float* __restrict__ kldG,
                                           int* __restrict__ doneRT,
                                           int* __restrict__ gq,
                                           float* __restrict__ out) {
    const int ct = blockIdx.x;   // 0..10
    const int rt = blockIdx.y;   // 0..15
    const int t = threadIdx.x;
    const int w = t >> 6, lane = t & 63;
    const int wm = w >> 1, wn = w & 1;
    const int quad = lane >> 4, l16 = lane & 15;
    __shared__ SMem sm;
    floatx4 acc[2][4] = {};
    const int row0 = rt * 64, col0 = ct * 128;

    // ================= Phase 1: GEMM + epilogue (identical to round-5 k2) =================
    const int rA0 = t >> 3, koA = (t & 7) * 8;
    const int rA1 = (256 + t) >> 3;
    const int rB0 = t >> 3;
    const ushort* pA0 = hB + (row0 + rA0) * 1024 + koA;
    const ushort* pA1 = hB + (row0 + rA1) * 1024 + koA;
    const ushort* pB  = Wt + (col0 + rB0) * 1024 + koA;

    short8 ra[2], rb[4];
    ra[0] = *(const short8*)(pA0);
    ra[1] = *(const short8*)(pA1);
    #pragma unroll
    for (int i = 0; i < 4; i++) rb[i] = *(const short8*)(pB + i * 32 * 1024);

    for (int ch = 0; ch < 16; ch++) {
        __syncthreads();
        *(short8*)&sm.g.As[rA0][koA] = ra[0];
        *(short8*)&sm.g.As[rA1][koA] = ra[1];
        #pragma unroll
        for (int i = 0; i < 4; i++) *(short8*)&sm.g.Bs[i * 32 + rB0][koA] = rb[i];
        __syncthreads();
        if (ch < 15) {
            const int off = (ch + 1) * 64;
            ra[0] = *(const short8*)(pA0 + off);
            ra[1] = *(const short8*)(pA1 + off);
            #pragma unroll
            for (int i = 0; i < 4; i++) rb[i] = *(const short8*)(pB + i * 32 * 1024 + off);
        }
        #pragma unroll
        for (int kk = 0; kk < 2; kk++) {
            int ko = kk * 32 + quad * 8;
            short8 a0 = *(const short8*)&sm.g.As[wm * 32 + l16][ko];
            short8 a1 = *(const short8*)&sm.g.As[wm * 32 + 16 + l16][ko];
            short8 b0 = *(const short8*)&sm.g.Bs[wn * 64 + l16][ko];
            short8 b1 = *(const short8*)&sm.g.Bs[wn * 64 + 16 + l16][ko];
            short8 b2 = *(const short8*)&sm.g.Bs[wn * 64 + 32 + l16][ko];
            short8 b3 = *(const short8*)&sm.g.Bs[wn * 64 + 48 + l16][ko];
            acc[0][0] = __builtin_amdgcn_mfma_f32_16x16x32_bf16(a0, b0, acc[0][0], 0, 0, 0);
            acc[0][1] = __builtin_amdgcn_mfma_f32_16x16x32_bf16(a0, b1, acc[0][1], 0, 0, 0);
            acc[0][2] = __builtin_amdgcn_mfma_f32_16x16x32_bf16(a0, b2, acc[0][2], 0, 0, 0);
            acc[0][3] = __builtin_amdgcn_mfma_f32_16x16x32_bf16(a0, b3, acc[0][3], 0, 0, 0);
            acc[1][0] = __builtin_amdgcn_mfma_f32_16x16x32_bf16(a1, b0, acc[1][0], 0, 0, 0);
            acc[1][1] = __builtin_amdgcn_mfma_f32_16x16x32_bf16(a1, b1, acc[1][1], 0, 0, 0);
            acc[1][2] = __builtin_amdgcn_mfma_f32_16x16x32_bf16(a1, b2, acc[1][2], 0, 0, 0);
            acc[1][3] = __builtin_amdgcn_mfma_f32_16x16x32_bf16(a1, b3, acc[1][3], 0, 0, 0);
        }
    }

    #pragma unroll
    for (int mi = 0; mi < 2; mi++) {
        const int grow = row0 + wm * 32 + mi * 16 + quad * 4;
        const int b = grow >> 2;
        float sn0 = 0.f, sn1 = 0.f, sn2 = 0.f, sn3 = 0.f;
        #pragma unroll
        for (int ni = 0; ni < 4; ni++) {
            int gc = col0 + wn * 64 + ni * 16 + l16;
            floatx4 a = acc[mi][ni];
            if (gc < EE) {
                float bias = bA[gc];
                float l0 = a[0] + bias, l1 = a[1] + bias, l2 = a[2] + bias, l3 = a[3] + bias;
                Lbar[b * EE + gc] = 0.25f * (l0 + l1 + l2 + l3);
                sn0 += logsigm(l0); sn1 += logsigm(l1); sn2 += logsigm(l2); sn3 += logsigm(l3);
            } else if (gc < CTOT) {
                int c2 = gc - EE;
                float bias = bF[c2];
                lgF[(b * 4 + 0) * 150 + c2] = a[0] + bias;
                lgF[(b * 4 + 1) * 150 + c2] = a[1] + bias;
                lgF[(b * 4 + 2) * 150 + c2] = a[2] + bias;
                lgF[(b * 4 + 3) * 150 + c2] = a[3] + bias;
            }
        }
        #pragma unroll
        for (int msk = 1; msk < 16; msk <<= 1) {
            sn0 += __shfl_xor(sn0, msk);
            sn1 += __shfl_xor(sn1, msk);
            sn2 += __shfl_xor(sn2, msk);
            sn3 += __shfl_xor(sn3, msk);
        }
        if (l16 == 0) {
            atomicAdd(&Sneg[b * 4 + 0], sn0);
            atomicAdd(&Sneg[b * 4 + 1], sn1);
            atomicAdd(&Sneg[b * 4 + 2], sn2);
            atomicAdd(&Sneg[b * 4 + 3], sn3);
        }
    }

    // release: all Lbar/lgF stores + Sneg atomics of this block done
    __syncthreads();
    __threadfence();
    if (t == 0) atomicAdd(&doneRT[rt], 1);

    // ================= Phase 2: work-stealing per-graph finalization =================
    // inverse permutations are graph-independent: build once per block
    for (int x = t; x < PP * NN; x += 256) {
        int p = x / NN, i = x - p * NN;
        sm.f.ip[p * NN + perms[x]] = i;
    }

    for (;;) {
        if (t == 0) sm.f.gcur = atomicAdd(gq, 1);
        __syncthreads();
        const int g = sm.f.gcur;
        if (g >= 256) break;
        const int rtn = g >> 4;
        if (t == 0) {
            while (atomicAdd(&doneRT[rtn], 0) < 11) {}
        }
        __syncthreads();
        __threadfence();   // acquire: invalidate stale cached lines before reading Lbar/lgF

        const int ne = cntG[g];
        for (int x = t; x < EE; x += 256) sm.f.Lb[x] = Lbar[g * EE + x];
        for (int x = t; x < 600; x += 256) sm.f.lgfs[x] = lgF[g * 600 + x];
        if (t < ne) sm.f.edges[t] = edgesG[g * 256 + t];
        __syncthreads();

        // Fx terms: wave w handles sample m = w
        {
            float l0 = 0.f, l1 = 0.f, l2 = -INFINITY, x0 = 0.f, x1 = 0.f, x2 = 0.f;
            bool v = lane < NN;
            if (v) {
                l0 = sm.f.lgfs[w * 150 + lane * 3 + 0];
                l1 = sm.f.lgfs[w * 150 + lane * 3 + 1];
                l2 = sm.f.lgfs[w * 150 + lane * 3 + 2];
                x0 = Fx[g * 150 + lane * 3 + 0];
                x1 = Fx[g * 150 + lane * 3 + 1];
                x2 = Fx[g * 150 + lane * 3 + 2];
            }
            float mx = wmax64(l2);
            float es = v ? expf(l2 - mx) : 0.f;
            es = wsum64(es);
            float lse = mx + logf(es);
            float val = 0.f;
            if (v) {
                val = coeff[0] * (logsigm(l0) + x0 * l0)
                    + coeff[1] * (logsigm(l1) + x1 * l1)
                    + coeff[2] * (x2 * (l2 - lse));
            }
            val = wsum64(val);
            if (lane == 0) sm.f.mred[w] = val;
        }
        __syncthreads();

        float lmax = -INFINITY;
        for (int p = w; p < PP; p += 4) {
            const int* ipp = &sm.f.ip[p * NN];
            float acc2 = 0.f;
            for (int x = lane; x < ne; x += 64) {
                int ed = sm.f.edges[x];
                int iu = ipp[ed >> 8], iv = ipp[ed & 255];
                int ii = max(iu, iv), jj = min(iu, iv);
                acc2 += sm.f.Lb[ii * (ii - 1) / 2 + jj];
            }
            acc2 = wsum64(acc2);
            lmax = fmaxf(lmax, acc2);
        }
        if (lane == 0) sm.f.wmaxs[w] = lmax;
        __syncthreads();
        if (t == 0) {
            float dmax = fmaxf(fmaxf(sm.f.wmaxs[0], sm.f.wmaxs[1]), fmaxf(sm.f.wmaxs[2], sm.f.wmaxs[3]));
            float sbar = 0.25f * (Sneg[g * 4 + 0] + Sneg[g * 4 + 1] + Sneg[g * 4 + 2] + Sneg[g * 4 + 3]);
            float fxv  = 0.25f * (sm.f.mred[0] + sm.f.mred[1] + sm.f.mred[2] + sm.f.mred[3]);
            out[g] = (sbar + dmax) + fxv - kldG[g];
        }
        __syncthreads();
    }
}

extern "C" void kernel_launch(void* const* d_in, const int* in_sizes, int n_in,
                              void* d_out, int out_size, void* d_ws, size_t ws_size,
                              hipStream_t stream) {
    const float* mean   = (const float*)d_in[0];
    const float* logvar = (const float*)d_in[1];
    const float* eps    = (const float*)d_in[2];
    const float* W1     = (const float*)d_in[3];
    const float* b1     = (const float*)d_in[4];
    const float* WA     = (const float*)d_in[5];
    const float* bA     = (const float*)d_in[6];
    const float* WF     = (const float*)d_in[7];
    const float* bF     = (const float*)d_in[8];
    const float* A      = (const float*)d_in[9];
    const float* Fx     = (const float*)d_in[10];
    const float* coeff  = (const float*)d_in[11];
    const int*   perms  = (const int*)d_in[12];
    float* out = (float*)d_out;

    ushort* Wt   = (ushort*)d_ws;               // 1408*1024 bf16
    ushort* hB   = Wt + NPAD * 1024;            // 1024*1024 bf16
    float*  Lbar = (float*)(hB + 1024 * 1024);  // 256*1225
    float*  Sneg = Lbar + BB * EE;              // 1024 (zeroed by kA)
    float*  lgF  = Sneg + 1024;                 // 1024*150
    int*    edgesG = (int*)(lgF + 1024 * 150);  // 256*256
    int*    cntG   = edgesG + 256 * 256;        // 256
    float*  kldG   = (float*)(cntG + 256);      // 256
    int*    doneRT = (int*)(kldG + 256);        // 16 (zeroed by kA)
    int*    gq     = doneRT + 16;               // 1  (zeroed by kA)

    kA<<<dim3(608), dim3(256), 0, stream>>>(mean, logvar, eps, W1, b1, WA, WF, A,
                                            hB, Wt, Sneg, edgesG, cntG, kldG, doneRT, gq);
    k24<<<dim3(11, 16), dim3(256), 0, stream>>>(hB, Wt, bA, bF, Fx, coeff, perms,
                                                Lbar, Sneg, lgF, edgesG, cntG, kldG,
                                                doneRT, gq, out);
}

// Round 7
// 136.052 us; speedup vs baseline: 1.3407x; 1.3407x over previous
//
#include <hip/hip_runtime.h>
#include <math.h>

// Problem constants
#define MM 4
#define BB 256
#define KK 64
#define HH 1024
#define NN 50
#define EE 1225
#define PP 64
#define CTOT 1375   // E + N*3
#define NPAD 1408   // cols padded to 11*128

typedef short short8 __attribute__((ext_vector_type(8)));
typedef float floatx4 __attribute__((ext_vector_type(4)));
typedef unsigned short ushort;

__device__ __forceinline__ ushort f2bf(float f) {
    union { float f; unsigned u; } v; v.f = f;
    unsigned r = v.u + 0x7fffu + ((v.u >> 16) & 1u);
    return (ushort)(r >> 16);
}

__device__ __forceinline__ float logsigm(float l) {
    // log sigmoid(-l) = -(max(l,0) + log1p(exp(-|l|)))
    return -(fmaxf(l, 0.0f) + log1pf(expf(-fabsf(l))));
}

__device__ __forceinline__ float wsum64(float v) {
    #pragma unroll
    for (int m = 1; m < 64; m <<= 1) v += __shfl_xor(v, m);
    return v;
}
__device__ __forceinline__ float wmax64(float v) {
    #pragma unroll
    for (int m = 1; m < 64; m <<= 1) v = fmaxf(v, __shfl_xor(v, m));
    return v;
}

// kA: fused weight transpose (blocks 256..607) + per-graph work (blocks 0..255):
//   h = relu(Z@W1+b1) -> bf16, edge extraction from A, KLD, Sneg zero-init.
// NOTE (R4/R6 post-mortems): keep this a plain 3-kernel chain. Cooperative
// grid-sync fusion cost +78 us; atomic producer-consumer fusion cost +46 us.
// Kernel-boundary gaps (~3-5 us each) are the cheapest sync on 8-XCD CDNA4.
__global__ __launch_bounds__(256) void kA(const float* __restrict__ mean,
                                          const float* __restrict__ logvar,
                                          const float* __restrict__ eps,
                                          const float* __restrict__ W1,
                                          const float* __restrict__ b1,
                                          const float* __restrict__ WA,
                                          const float* __restrict__ WF,
                                          const float* __restrict__ A,
                                          ushort* __restrict__ hB,
                                          ushort* __restrict__ Wt,
                                          float* __restrict__ Sneg,
                                          int*   __restrict__ edgesG,
                                          int*   __restrict__ cntG,
                                          float* __restrict__ kldG) {
    const int t = threadIdx.x;
    __shared__ float smem[64 * 65];
    __shared__ int cnt;

    if (blockIdx.x < 256) {
        // ---- per-graph block ----
        const int b = blockIdx.x;
        float4* z4 = (float4*)smem;
        if (t == 0) cnt = 0;
        if (t < 64) {
            float mv = mean[b * 64 + t];
            float lv = logvar[b * 64 + t];
            float sd = expf(0.5f * lv);
            float4 z;
            z.x = mv + sd * eps[(0 * BB + b) * 64 + t];
            z.y = mv + sd * eps[(1 * BB + b) * 64 + t];
            z.z = mv + sd * eps[(2 * BB + b) * 64 + t];
            z.w = mv + sd * eps[(3 * BB + b) * 64 + t];
            z4[t] = z;
            // KLD (wave 0, one lane per latent dim)
            float term = 0.5f * (expf(lv) + mv * mv - 1.0f - lv);
            term = wsum64(term);
            if (t == 0) kldG[b] = term;
        }
        if (t < 4) Sneg[b * 4 + t] = 0.0f;
        __syncthreads();
        const int j0 = t * 4;
        float acc[4][4] = {};   // [m][jc]
        #pragma unroll 8
        for (int k = 0; k < 64; k++) {
            float4 w = *(const float4*)&W1[k * HH + j0];
            float4 z = z4[k];
            acc[0][0] += z.x * w.x; acc[0][1] += z.x * w.y; acc[0][2] += z.x * w.z; acc[0][3] += z.x * w.w;
            acc[1][0] += z.y * w.x; acc[1][1] += z.y * w.y; acc[1][2] += z.y * w.z; acc[1][3] += z.y * w.w;
            acc[2][0] += z.z * w.x; acc[2][1] += z.z * w.y; acc[2][2] += z.z * w.z; acc[2][3] += z.z * w.w;
            acc[3][0] += z.w * w.x; acc[3][1] += z.w * w.y; acc[3][2] += z.w * w.z; acc[3][3] += z.w * w.w;
        }
        float4 bb = *(const float4*)&b1[j0];
        #pragma unroll
        for (int m = 0; m < 4; m++) {
            unsigned u0 = ((unsigned)f2bf(fmaxf(acc[m][0] + bb.x, 0.f))) |
                          ((unsigned)f2bf(fmaxf(acc[m][1] + bb.y, 0.f)) << 16);
            unsigned u1 = ((unsigned)f2bf(fmaxf(acc[m][2] + bb.z, 0.f))) |
                          ((unsigned)f2bf(fmaxf(acc[m][3] + bb.w, 0.f)) << 16);
            uint2 u; u.x = u0; u.y = u1;
            *(uint2*)&hB[(b * 4 + m) * HH + j0] = u;
        }
        // ---- edge extraction: coalesced scan of A[b], lower triangle ----
        for (int x = t; x < 2500; x += 256) {
            int i = x / NN, j = x - i * NN;
            if (j < i) {
                float a = A[b * 2500 + x];
                if (a != 0.0f) { int id = atomicAdd(&cnt, 1); edgesG[b * 256 + id] = (i << 8) | j; }
            }
        }
        __syncthreads();
        if (t == 0) cntG[b] = cnt;
    } else {
        // ---- Wt[n][k] = transpose of [WA | WF] (bf16, zero-padded cols) ----
        const int id = blockIdx.x - 256;
        const int kt = id & 15, nt = id >> 4;
        float* T = smem;   // [64][65]
        const int k0 = kt * 64, n0 = nt * 64;
        #pragma unroll
        for (int i = 0; i < 16; i++) {
            int x = i * 256 + t;
            int kk = x >> 6, nn = x & 63;
            int gn = n0 + nn, gk = k0 + kk;
            float v = 0.f;
            if (gn < EE)        v = WA[gk * EE + gn];
            else if (gn < CTOT) v = WF[gk * 150 + (gn - EE)];
            T[kk * 65 + nn] = v;
        }
        __syncthreads();
        #pragma unroll
        for (int i = 0; i < 16; i++) {
            int x = i * 256 + t;
            int nn = x >> 6, kk = x & 63;
            Wt[(n0 + nn) * 1024 + k0 + kk] = f2bf(T[kk * 65 + nn]);
        }
    }
}

// K2: MFMA GEMM logits[1024][1375] = hB @ Wt^T with fused epilogue + register
// double-buffer prefetch. Block tile 64x128, 4 waves (2x2), wave 32x64 = 2x4 MFMA 16x16x32.
__global__ __launch_bounds__(256) void k2(const ushort* __restrict__ hB,
                                          const ushort* __restrict__ Wt,
                                          const float* __restrict__ bA,
                                          const float* __restrict__ bF,
                                          float* __restrict__ Lbar,
                                          float* __restrict__ Sneg,
                                          float* __restrict__ lgF) {
    const int ct = blockIdx.x;   // 0..10
    const int rt = blockIdx.y;   // 0..15
    const int t = threadIdx.x;
    const int w = t >> 6, lane = t & 63;
    const int wm = w >> 1, wn = w & 1;
    const int quad = lane >> 4, l16 = lane & 15;
    __shared__ short As[64][72];
    __shared__ short Bs[128][72];
    floatx4 acc[2][4] = {};
    const int row0 = rt * 64, col0 = ct * 128;

    const int rA0 = t >> 3, koA = (t & 7) * 8;
    const int rA1 = (256 + t) >> 3;
    const int rB0 = t >> 3;
    const ushort* pA0 = hB + (row0 + rA0) * 1024 + koA;
    const ushort* pA1 = hB + (row0 + rA1) * 1024 + koA;
    const ushort* pB  = Wt + (col0 + rB0) * 1024 + koA;

    short8 ra[2], rb[4];
    ra[0] = *(const short8*)(pA0);
    ra[1] = *(const short8*)(pA1);
    #pragma unroll
    for (int i = 0; i < 4; i++) rb[i] = *(const short8*)(pB + i * 32 * 1024);

    for (int ch = 0; ch < 16; ch++) {
        __syncthreads();
        *(short8*)&As[rA0][koA] = ra[0];
        *(short8*)&As[rA1][koA] = ra[1];
        #pragma unroll
        for (int i = 0; i < 4; i++) *(short8*)&Bs[i * 32 + rB0][koA] = rb[i];
        __syncthreads();
        if (ch < 15) {
            const int off = (ch + 1) * 64;
            ra[0] = *(const short8*)(pA0 + off);
            ra[1] = *(const short8*)(pA1 + off);
            #pragma unroll
            for (int i = 0; i < 4; i++) rb[i] = *(const short8*)(pB + i * 32 * 1024 + off);
        }
        #pragma unroll
        for (int kk = 0; kk < 2; kk++) {
            int ko = kk * 32 + quad * 8;
            short8 a0 = *(const short8*)&As[wm * 32 + l16][ko];
            short8 a1 = *(const short8*)&As[wm * 32 + 16 + l16][ko];
            short8 b0 = *(const short8*)&Bs[wn * 64 + l16][ko];
            short8 b1 = *(const short8*)&Bs[wn * 64 + 16 + l16][ko];
            short8 b2 = *(const short8*)&Bs[wn * 64 + 32 + l16][ko];
            short8 b3 = *(const short8*)&Bs[wn * 64 + 48 + l16][ko];
            acc[0][0] = __builtin_amdgcn_mfma_f32_16x16x32_bf16(a0, b0, acc[0][0], 0, 0, 0);
            acc[0][1] = __builtin_amdgcn_mfma_f32_16x16x32_bf16(a0, b1, acc[0][1], 0, 0, 0);
            acc[0][2] = __builtin_amdgcn_mfma_f32_16x16x32_bf16(a0, b2, acc[0][2], 0, 0, 0);
            acc[0][3] = __builtin_amdgcn_mfma_f32_16x16x32_bf16(a0, b3, acc[0][3], 0, 0, 0);
            acc[1][0] = __builtin_amdgcn_mfma_f32_16x16x32_bf16(a1, b0, acc[1][0], 0, 0, 0);
            acc[1][1] = __builtin_amdgcn_mfma_f32_16x16x32_bf16(a1, b1, acc[1][1], 0, 0, 0);
            acc[1][2] = __builtin_amdgcn_mfma_f32_16x16x32_bf16(a1, b2, acc[1][2], 0, 0, 0);
            acc[1][3] = __builtin_amdgcn_mfma_f32_16x16x32_bf16(a1, b3, acc[1][3], 0, 0, 0);
        }
    }

    // Epilogue: C/D layout col=lane&15, row=quad*4+reg -> lane's 4 regs = graph b, m=0..3
    #pragma unroll
    for (int mi = 0; mi < 2; mi++) {
        const int grow = row0 + wm * 32 + mi * 16 + quad * 4;
        const int b = grow >> 2;
        float sn0 = 0.f, sn1 = 0.f, sn2 = 0.f, sn3 = 0.f;
        #pragma unroll
        for (int ni = 0; ni < 4; ni++) {
            int gc = col0 + wn * 64 + ni * 16 + l16;
            floatx4 a = acc[mi][ni];
            if (gc < EE) {
                float bias = bA[gc];
                float l0 = a[0] + bias, l1 = a[1] + bias, l2 = a[2] + bias, l3 = a[3] + bias;
                Lbar[b * EE + gc] = 0.25f * (l0 + l1 + l2 + l3);
                sn0 += logsigm(l0); sn1 += logsigm(l1); sn2 += logsigm(l2); sn3 += logsigm(l3);
            } else if (gc < CTOT) {
                int c2 = gc - EE;
                float bias = bF[c2];
                lgF[(b * 4 + 0) * 150 + c2] = a[0] + bias;
                lgF[(b * 4 + 1) * 150 + c2] = a[1] + bias;
                lgF[(b * 4 + 2) * 150 + c2] = a[2] + bias;
                lgF[(b * 4 + 3) * 150 + c2] = a[3] + bias;
            }
        }
        #pragma unroll
        for (int msk = 1; msk < 16; msk <<= 1) {
            sn0 += __shfl_xor(sn0, msk);
            sn1 += __shfl_xor(sn1, msk);
            sn2 += __shfl_xor(sn2, msk);
            sn3 += __shfl_xor(sn3, msk);
        }
        if (l16 == 0) {
            atomicAdd(&Sneg[b * 4 + 0], sn0);
            atomicAdd(&Sneg[b * 4 + 1], sn1);
            atomicAdd(&Sneg[b * 4 + 2], sn2);
            atomicAdd(&Sneg[b * 4 + 3], sn3);
        }
    }
}

// K4: per-graph finalization. grid 256, 256 threads (4 waves).
// Edges + KLD precomputed by kA; no A-scan here.
__global__ __launch_bounds__(256) void k4(const float* __restrict__ Fx,
                                          const float* __restrict__ coeff,
                                          const int* __restrict__ perms,
                                          const float* __restrict__ Lbar,
                                          const float* __restrict__ Sneg,
                                          const float* __restrict__ lgF,
                                          const int* __restrict__ edgesG,
                                          const int* __restrict__ cntG,
                                          const float* __restrict__ kldG,
                                          float* __restrict__ out) {
    const int b = blockIdx.x;
    const int t = threadIdx.x;
    const int w = t >> 6, lane = t & 63;
    __shared__ int   ip[PP * NN];
    __shared__ float Lb[EE];
    __shared__ int   edges[256];
    __shared__ float lgfs[600];
    __shared__ float mred[4], wmaxs[4];

    const int ne = cntG[b];
    for (int x = t; x < PP * NN; x += 256) {
        int p = x / NN, i = x - p * NN;
        ip[p * NN + perms[x]] = i;
    }
    for (int x = t; x < EE; x += 256) Lb[x] = Lbar[b * EE + x];
    for (int x = t; x < 600; x += 256) lgfs[x] = lgF[b * 600 + x];
    if (t < ne) edges[t] = edgesG[b * 256 + t];
    __syncthreads();

    // Fx terms: wave w handles sample m = w
    {
        float l0 = 0.f, l1 = 0.f, l2 = -INFINITY, x0 = 0.f, x1 = 0.f, x2 = 0.f;
        bool v = lane < NN;
        if (v) {
            l0 = lgfs[w * 150 + lane * 3 + 0];
            l1 = lgfs[w * 150 + lane * 3 + 1];
            l2 = lgfs[w * 150 + lane * 3 + 2];
            x0 = Fx[b * 150 + lane * 3 + 0];
            x1 = Fx[b * 150 + lane * 3 + 1];
            x2 = Fx[b * 150 + lane * 3 + 2];
        }
        float mx = wmax64(l2);
        float es = v ? expf(l2 - mx) : 0.f;
        es = wsum64(es);
        float lse = mx + logf(es);
        float val = 0.f;
        if (v) {
            val = coeff[0] * (logsigm(l0) + x0 * l0)
                + coeff[1] * (logsigm(l1) + x1 * l1)
                + coeff[2] * (x2 * (l2 - lse));
        }
        val = wsum64(val);
        if (lane == 0) mred[w] = val;
    }
    __syncthreads();

    float lmax = -INFINITY;
    for (int p = w; p < PP; p += 4) {
        const int* ipp = &ip[p * NN];
        float acc = 0.f;
        for (int x = lane; x < ne; x += 64) {
            int ed = edges[x];
            int iu = ipp[ed >> 8], iv = ipp[ed & 255];
            int ii = max(iu, iv), jj = min(iu, iv);
            acc += Lb[ii * (ii - 1) / 2 + jj];
        }
        acc = wsum64(acc);
        lmax = fmaxf(lmax, acc);
    }
    if (lane == 0) wmaxs[w] = lmax;
    __syncthreads();
    if (t == 0) {
        float dmax = fmaxf(fmaxf(wmaxs[0], wmaxs[1]), fmaxf(wmaxs[2], wmaxs[3]));
        float sbar = 0.25f * (Sneg[b * 4 + 0] + Sneg[b * 4 + 1] + Sneg[b * 4 + 2] + Sneg[b * 4 + 3]);
        float fxv  = 0.25f * (mred[0] + mred[1] + mred[2] + mred[3]);
        out[b] = (sbar + dmax) + fxv - kldG[b];
    }
}

extern "C" void kernel_launch(void* const* d_in, const int* in_sizes, int n_in,
                              void* d_out, int out_size, void* d_ws, size_t ws_size,
                              hipStream_t stream) {
    const float* mean   = (const float*)d_in[0];
    const float* logvar = (const float*)d_in[1];
    const float* eps    = (const float*)d_in[2];
    const float* W1     = (const float*)d_in[3];
    const float* b1     = (const float*)d_in[4];
    const float* WA     = (const float*)d_in[5];
    const float* bA     = (const float*)d_in[6];
    const float* WF     = (const float*)d_in[7];
    const float* bF     = (const float*)d_in[8];
    const float* A      = (const float*)d_in[9];
    const float* Fx     = (const float*)d_in[10];
    const float* coeff  = (const float*)d_in[11];
    const int*   perms  = (const int*)d_in[12];
    float* out = (float*)d_out;

    ushort* Wt   = (ushort*)d_ws;               // 1408*1024 bf16
    ushort* hB   = Wt + NPAD * 1024;            // 1024*1024 bf16
    float*  Lbar = (float*)(hB + 1024 * 1024);  // 256*1225
    float*  Sneg = Lbar + BB * EE;              // 1024 (zeroed by kA)
    float*  lgF  = Sneg + 1024;                 // 1024*150
    int*    edgesG = (int*)(lgF + 1024 * 150);  // 256*256
    int*    cntG   = edgesG + 256 * 256;        // 256
    float*  kldG   = (float*)(cntG + 256);      // 256

    kA<<<dim3(608), dim3(256), 0, stream>>>(mean, logvar, eps, W1, b1, WA, WF, A,
                                            hB, Wt, Sneg, edgesG, cntG, kldG);
    k2<<<dim3(11, 16), dim3(256), 0, stream>>>(hB, Wt, bA, bF, Lbar, Sneg, lgF);
    k4<<<dim3(BB), dim3(256), 0, stream>>>(Fx, coeff, perms, Lbar, Sneg, lgF,
                                           edgesG, cntG, kldG, out);
}